// Round 1
// baseline (17265.349 us; speedup 1.0000x reference)
//
#include <hip/hip_runtime.h>

// ---------------------------------------------------------------------------
// SimpleGRU on MI355X (gfx950). Round 7: XCD-local sentinel-ring dataflow.
//   Round-6 (PASS, 3.00ms): global sentinel ring, 5.48us/step — period is
//     dominated by cross-XCD store->load visibility through L3 (flag protocol
//     with 2 device round trips cost 9.2us/step; 1 round trip costs 5.5us).
//   Now: batches are independent -> 8 groups x 8 batches, ONE GROUP PER XCD.
//   256 blocks (1/CU) register their HW_REG_XCC_ID via device atomics and
//   rendezvous (all co-resident: 49KB LDS => capacity >= grid). If every XCD
//   holds exactly 32 blocks: group=XCD, slice=ticket, consumers poll with
//   sc0 only -> exchange is served by the group's own L2 (~us -> ~100s ns).
//   Producers always store sc0 sc1 (L3 holds truth), so a 24-round poll
//   escalation to sc0 sc1 guarantees progress even if sc0 loads were L1-
//   sticky. Any other dispatch outcome -> unanimous deterministic fallback
//   to ticket-ordered groups with the proven sc0 sc1 protocol (= round-6
//   behavior). Strictly-backward deps within a group -> deadlock-free.
// ws: xg bf16 [512][1536][64] (100,663,296 B) |
//     ring [grp=8][depth][8][512] f16 (depth*65,536 B) | prog/regs int[288]
// ---------------------------------------------------------------------------

typedef unsigned short ushort_t;
typedef short short8      __attribute__((ext_vector_type(8)));
typedef float floatx4     __attribute__((ext_vector_type(4)));
typedef unsigned int uintx4 __attribute__((ext_vector_type(4)));
typedef unsigned short ushort4v __attribute__((ext_vector_type(4)));
typedef _Float16 half8    __attribute__((ext_vector_type(8)));

#define SEQL 512
#define BATCH 64
#define EMBD 256
#define HID 512
#define G3 1536
#define NOUT 5
#define NGRP 8                     // one group per XCD
#define GRPB 8                     // batches per group
#define NSLC 32                    // hidden-slice blocks per group
#define GSLOT 8192                 // per-group h snapshot: 8 x 512 x 2B
#define SLOT_TOT 65536             // all groups, one step: 8 x 8192
#define XG_BYTES 100663296

__device__ __forceinline__ float bf2f(ushort_t v){
  union { unsigned u; float f; } x; x.u = ((unsigned)v) << 16; return x.f;
}
__device__ __forceinline__ ushort_t f2bf(float f){
  unsigned u = __float_as_uint(f);
  return (ushort_t)((u + 0x7FFFu + ((u >> 16) & 1u)) >> 16);
}
__device__ __forceinline__ float sigm(float x){
  x = fminf(fmaxf(x, -20.f), 20.f);
  return 1.f / (1.f + __expf(-x));
}
__device__ __forceinline__ float tanh_c(float x){
  x = fminf(fmaxf(x, -10.f), 10.f);
  float e = __expf(2.f * x);
  return (e - 1.f) / (e + 1.f);
}
__device__ __forceinline__ bool has_sent(half8 v){
  union { half8 h; unsigned u[4]; } x; x.h = v;
  bool b = false;
  #pragma unroll
  for (int i = 0; i < 4; ++i){
    b |= ((x.u[i] & 0xFFFFu) == 0xFFFFu);
    b |= ((x.u[i] >> 16) == 0xFFFFu);
  }
  return b;
}

// --- K0: fill ring with sentinel 0xFFFF halves; zero prog[256]+regs[32] ---
__global__ __launch_bounds__(256) void gru_init(uintx4* __restrict__ ring16,
                                                int* __restrict__ prog){
  size_t i = (size_t)blockIdx.x * 256 + threadIdx.x;  // grid = depth*16 blocks
  uintx4 s = {0xFFFFFFFFu, 0xFFFFFFFFu, 0xFFFFFFFFu, 0xFFFFFFFFu};
  ring16[i] = s;
  if (i < 288) prog[i] = 0;
}

// --- K1: x_gates = emb[seq] @ w_ih^T + b_ih, bf16, layout [s][1536][64] ---
#define LDSIDX2(row, chunk) (((row) << 7) + ((((chunk) ^ ((row) & 7))) << 3))
__global__ __launch_bounds__(256) void gru_xgates(
    const int* __restrict__ seq, const float* __restrict__ emb,
    const float* __restrict__ w_ih, const float* __restrict__ b_ih,
    ushort_t* __restrict__ xg)
{
  __shared__ __align__(16) short lA[64 * 128];
  __shared__ __align__(16) short lB[64 * 128];
  const int tid   = threadIdx.x;
  const int sIdx  = blockIdx.x;
  const int nBase = blockIdx.y * 64;
  const int w    = tid >> 6;
  const int l    = tid & 63;
  const int l15  = l & 15;
  const int quad = l >> 4;
  floatx4 acc[4] = {};

  #pragma unroll
  for (int kp = 0; kp < 2; ++kp){
    __syncthreads();
    #pragma unroll
    for (int i = 0; i < 4; ++i){
      int lin = i * 256 + tid;
      int row = lin >> 4;
      int kc  = lin & 15;
      int kbase = kp * 128 + kc * 8;
      int token = seq[(sIdx << 6) + row];
      const float* srcA = emb  + (size_t)token * EMBD + kbase;
      const float* srcB = w_ih + (size_t)(nBase + row) * EMBD + kbase;
      floatx4 a0 = *(const floatx4*)(srcA);
      floatx4 a1 = *(const floatx4*)(srcA + 4);
      floatx4 b0 = *(const floatx4*)(srcB);
      floatx4 b1 = *(const floatx4*)(srcB + 4);
      short8 pa, pb;
      #pragma unroll
      for (int j = 0; j < 4; ++j){
        pa[j]     = (short)f2bf(a0[j]);
        pa[j + 4] = (short)f2bf(a1[j]);
        pb[j]     = (short)f2bf(b0[j]);
        pb[j + 4] = (short)f2bf(b1[j]);
      }
      *(short8*)&lA[LDSIDX2(row, kc)] = pa;
      *(short8*)&lB[LDSIDX2(row, kc)] = pb;
    }
    __syncthreads();
    #pragma unroll
    for (int kc = 0; kc < 4; ++kc){
      int chunk = kc * 4 + quad;
      short8 a = *(const short8*)&lA[LDSIDX2(w * 16 + l15, chunk)];
      #pragma unroll
      for (int s = 0; s < 4; ++s){
        short8 bf = *(const short8*)&lB[LDSIDX2(s * 16 + l15, chunk)];
        acc[s] = __builtin_amdgcn_mfma_f32_16x16x32_bf16(a, bf, acc[s], 0, 0, 0);
      }
    }
  }
  #pragma unroll
  for (int s = 0; s < 4; ++s){
    int g = nBase + s * 16 + l15;
    float bias = b_ih[g];
    ushort4v pk;
    #pragma unroll
    for (int r = 0; r < 4; ++r) pk[r] = f2bf(acc[s][r] + bias);
    *(ushort4v*)(xg + ((size_t)sIdx * G3 + g) * BATCH + (w * 16 + quad * 4)) = pk;
  }
}

// --- K2: XCD-grouped dataflow recurrence. 256 blocks x 256 threads.
//     Registration rendezvous -> (group, slice); wave 0 runs the loop. ---
__global__ __launch_bounds__(256, 1) void gru_rec(
    const ushort_t* __restrict__ xg, const float* __restrict__ whh,
    const float* __restrict__ bhh, const int* __restrict__ lengths,
    char* __restrict__ ring, int* __restrict__ prog, int depth)
{
  __shared__ __align__(16) _Float16 wlds[48 * 64 * 8];   // 49,152 B (B-frags)
  __shared__ __align__(16) _Float16 hscr[8 * 16];        //    256 B (repack)
  __shared__ int s_grp, s_slc, s_fast;
  const int tid  = threadIdx.x;
  const int w    = tid >> 6;
  const int l    = tid & 63;
  const int l15  = l & 15;
  const int quad = l >> 4;

  // ---- rendezvous + XCD-affinity group formation ----
  int* regs = prog + 256;              // [0]=gcount, [1..8]=per-XCD counts
  if (tid == 0){
    unsigned xcd;
    asm volatile("s_getreg_b32 %0, hwreg(HW_REG_XCC_ID)" : "=s"(xcd));
    xcd &= 7u;
    int myx = atomicAdd(&regs[1 + xcd], 1);
    asm volatile("s_waitcnt vmcnt(0)" ::: "memory");  // xcd count visible first
    int gt = atomicAdd(&regs[0], 1);
    int v;
    do {
      asm volatile("s_sleep 1" ::: "memory");
      asm volatile("global_load_dword %0, %1, off sc0 sc1\n\t"
                   "s_waitcnt vmcnt(0)"
                   : "=v"(v) : "v"(&regs[0]) : "memory");
    } while (v < NGRP * NSLC);
    // counts are final after full registration -> decision is unanimous
    int ok = 1;
    #pragma unroll
    for (int x = 0; x < 8; ++x){
      int c;
      asm volatile("global_load_dword %0, %1, off sc0 sc1\n\t"
                   "s_waitcnt vmcnt(0)"
                   : "=v"(c) : "v"(&regs[1 + x]) : "memory");
      ok &= (c == NSLC);
    }
    s_fast = ok;
    s_grp  = ok ? (int)xcd   : ((gt >> 5) & 7);
    s_slc  = ok ? (myx & 31) : (gt & 31);
  }
  __syncthreads();
  const int grp  = s_grp;
  const int g    = s_slc;              // hidden slice [g*16, g*16+16)
  const int fast = s_fast;
  const int j    = g * 16 + l15;       // this lane's hidden unit

  // ---- setup: 48 W_hh rows f32->f16 into B-frag LDS (all 4 waves) ----
  #pragma unroll
  for (int i = 0; i < 12; ++i){
    int p  = i * 4 + w;                 // 0..47
    int G  = p >> 4;                    // gate (0=r,1=z,2=n)
    int ks = p & 15;                    // K-step
    const float* src = whh + (size_t)(G * HID + j) * HID + ks * 32 + quad * 8;
    floatx4 f0 = *(const floatx4*)(src);
    floatx4 f1 = *(const floatx4*)(src + 4);
    half8 hv;
    #pragma unroll
    for (int q = 0; q < 4; ++q){ hv[q] = (_Float16)f0[q]; hv[q + 4] = (_Float16)f1[q]; }
    *(half8*)&wlds[((size_t)p * 64 + l) * 8] = hv;
  }
  __syncthreads();
  if (tid >= 64) return;               // wave 0 runs the recurrence alone

  char* gring = ring + (size_t)grp * depth * GSLOT;
  const int   row  = l15 & 7;          // A-row polled (rows 8-15 mirror 0-7)
  const int   bloc = (quad & 1) * 4;   // local batch base (quads 2,3 mirror)
  const int   gb   = grp * GRPB + bloc;
  const float bhR = bhh[j], bhZ = bhh[HID + j], bhN = bhh[2 * HID + j];
  int   len[4];
  float h[4];
  #pragma unroll
  for (int r = 0; r < 4; ++r){ len[r] = lengths[gb + r]; h[r] = 0.f; }
  const int Lmax  = lengths[grp * GRPB];  // group max (sorted descending)
  const int mask  = depth - 1;
  const bool reuse = (depth < Lmax);
  int cmin = 0;

  for (int t = 0; t < Lmax; ++t){
    // 0) ring-reuse guard (off critical path when depth >= Lmax)
    if (reuse && t >= depth){
      int target = t - depth + 2;
      if (cmin < target){
        int tgt2 = target + 4;          // slack; publishes every 8 guarantee progress
        while (true){
          int p0;
          asm volatile("global_load_dword %0, %1, off sc0 sc1\n\t"
                       "s_waitcnt vmcnt(0)"
                       : "=v"(p0) : "v"(prog + grp * NSLC + (l & 31)) : "memory");
          if (__all(p0 >= tgt2)) break;
        }
        cmin = tgt2;
      }
    }

    // 1) xg prefetch (independent of h)
    const ushort_t* xt = xg + (size_t)t * G3 * BATCH;
    ushort4v xR = __builtin_nontemporal_load(
        (const ushort4v*)(xt + (size_t)(          j) * BATCH + gb));
    ushort4v xZ = __builtin_nontemporal_load(
        (const ushort4v*)(xt + (size_t)(HID     + j) * BATCH + gb));
    ushort4v xN = __builtin_nontemporal_load(
        (const ushort4v*)(xt + (size_t)(2 * HID + j) * BATCH + gb));

    // 2) consume h(t-1): poll own A-chunks until non-sentinel, then MFMA.
    //    fast path = sc0 (group-local L2); escalate to sc0 sc1 after 24
    //    rounds (always correct: stores are write-through to L3).
    floatx4 aR = {0.f,0.f,0.f,0.f}, aZ = {0.f,0.f,0.f,0.f}, aN = {0.f,0.f,0.f,0.f};
    if (t > 0){
      const char* rowp = gring + (size_t)((t - 1) & mask) * GSLOT
                       + (size_t)row * 1024 + quad * 16;
      half8 aF[16];
      int rounds = 0;
      while (true){
        if (fast && rounds < 24){
          #pragma unroll
          for (int ks = 0; ks < 16; ++ks){
            const char* pa = rowp + ks * 64;
            asm volatile("global_load_dwordx4 %0, %1, off sc0"
                         : "=v"(aF[ks]) : "v"(pa) : "memory");
          }
        } else {
          #pragma unroll
          for (int ks = 0; ks < 16; ++ks){
            const char* pa = rowp + ks * 64;
            asm volatile("global_load_dwordx4 %0, %1, off sc0 sc1"
                         : "=v"(aF[ks]) : "v"(pa) : "memory");
          }
        }
        asm volatile("s_waitcnt vmcnt(0)"
                     : "+v"(aF[0]),  "+v"(aF[1]),  "+v"(aF[2]),  "+v"(aF[3]),
                       "+v"(aF[4]),  "+v"(aF[5]),  "+v"(aF[6]),  "+v"(aF[7]),
                       "+v"(aF[8]),  "+v"(aF[9]),  "+v"(aF[10]), "+v"(aF[11]),
                       "+v"(aF[12]), "+v"(aF[13]), "+v"(aF[14]), "+v"(aF[15])
                     :: "memory");
        bool bad = false;
        #pragma unroll
        for (int ks = 0; ks < 16; ++ks) bad |= has_sent(aF[ks]);
        if (!__any(bad)) break;
        ++rounds;
      }
      #pragma unroll
      for (int ks = 0; ks < 16; ++ks){
        half8 a  = aF[ks];
        half8 b0 = *(const half8*)&wlds[((size_t)(0 * 16 + ks) * 64 + l) * 8];
        half8 b1 = *(const half8*)&wlds[((size_t)(1 * 16 + ks) * 64 + l) * 8];
        half8 b2 = *(const half8*)&wlds[((size_t)(2 * 16 + ks) * 64 + l) * 8];
        aR = __builtin_amdgcn_mfma_f32_16x16x32_f16(a, b0, aR, 0, 0, 0);
        aZ = __builtin_amdgcn_mfma_f32_16x16x32_f16(a, b1, aZ, 0, 0, 0);
        aN = __builtin_amdgcn_mfma_f32_16x16x32_f16(a, b2, aN, 0, 0, 0);
      }
      // restore sentinel on consumed chunks (reuse mode; rows 0-7 only)
      if (reuse && l15 < 8){
        uintx4 sv = {0xFFFFFFFFu, 0xFFFFFFFFu, 0xFFFFFFFFu, 0xFFFFFFFFu};
        #pragma unroll
        for (int ks = 0; ks < 16; ++ks){
          const char* pa = rowp + ks * 64;
          asm volatile("global_store_dwordx4 %0, %1, off sc0 sc1"
                       :: "v"(pa), "v"(sv) : "memory");
        }
      }
    }

    // 3) gates + h update (f32 carry). C rows quad*4+r; quads 2,3 mirror.
    #pragma unroll
    for (int r = 0; r < 4; ++r){
      float rr = sigm(bf2f(xR[r]) + aR[r] + bhR);
      float zz = sigm(bf2f(xZ[r]) + aZ[r] + bhZ);
      float nn = tanh_c(bf2f(xN[r]) + rr * (aN[r] + bhN));
      float hn = (1.f - zz) * nn + zz * h[r];
      h[r] = (t < len[r]) ? hn : h[r];
    }

    // 4) intra-wave repack via LDS, publish h(t) chunks (fire-and-forget;
    //    sc1 keeps L3 truthful for escalated/slow readers and K3)
    if (quad < 2){
      #pragma unroll
      for (int r = 0; r < 4; ++r) hscr[(bloc + r) * 16 + l15] = (_Float16)h[r];
    }
    asm volatile("s_waitcnt lgkmcnt(0)" ::: "memory");   // wave-local DS order
    if (l < 16){
      int bl = l >> 1;                  // group-local batch 0..7
      int hc = l & 1;                   // which 8-wide half of the 16-slice
      half8 ch = *(const half8*)&hscr[bl * 16 + hc * 8];
      const char* dst = gring + (size_t)(t & mask) * GSLOT
                      + (size_t)bl * 1024 + (size_t)g * 32 + (size_t)hc * 16;
      asm volatile("global_store_dwordx4 %0, %1, off sc0 sc1"
                   :: "v"(dst), "v"(ch) : "memory");
    }

    // 5) coarse progress publish (reuse mode only), ordered after restores
    if (reuse && ((t & 7) == 7)){
      asm volatile("s_waitcnt vmcnt(0)" ::: "memory");
      if (l == 0){
        const int* pp = prog + (grp * NSLC + g);
        int pv = t + 1;
        asm volatile("global_store_dword %0, %1, off sc0 sc1"
                     :: "v"(pp), "v"(pv) : "memory");
      }
    }
  }
}

// --- K3: logits + log_softmax from group ring slot (Lg-1). 64 x 64 thr. ---
__global__ __launch_bounds__(64) void gru_out(
    const char* __restrict__ ring, const int* __restrict__ lengths,
    const float* __restrict__ wout, const float* __restrict__ bout,
    float* __restrict__ out, int depth)
{
  const int b = blockIdx.x, l = threadIdx.x;
  const int grp = b >> 3;
  const int Lg  = lengths[grp << 3];   // group's max length (sorted desc)
  const _Float16* h = (const _Float16*)(ring
      + ((size_t)grp * depth + (size_t)((Lg - 1) & (depth - 1))) * GSLOT
      + (size_t)(b & 7) * 1024);
  half8 hv = *(const half8*)(h + l * 8);
  float p[NOUT];
  #pragma unroll
  for (int o = 0; o < NOUT; ++o){
    const float* wr = wout + o * HID + l * 8;
    float a = 0.f;
    #pragma unroll
    for (int i = 0; i < 8; ++i) a += wr[i] * (float)hv[i];
    #pragma unroll
    for (int d = 32; d >= 1; d >>= 1) a += __shfl_down(a, d, 64);
    p[o] = a;
  }
  if (l == 0){
    float lg[NOUT], m = -1e30f;
    #pragma unroll
    for (int o = 0; o < NOUT; ++o){
      float v = p[o] + bout[o];
      if (!(v == v)) v = -1.0f;
      lg[o] = v; m = fmaxf(m, v);
    }
    float ssum = 0.f;
    #pragma unroll
    for (int o = 0; o < NOUT; ++o) ssum += __expf(lg[o] - m);
    float ls = __logf(ssum);
    #pragma unroll
    for (int o = 0; o < NOUT; ++o) out[b * NOUT + o] = lg[o] - m - ls;
  }
}

extern "C" void kernel_launch(void* const* d_in, const int* in_sizes, int n_in,
                              void* d_out, int out_size, void* d_ws, size_t ws_size,
                              hipStream_t stream) {
  (void)in_sizes; (void)n_in; (void)out_size;
  const int*   seq     = (const int*)d_in[0];
  const int*   lengths = (const int*)d_in[1];
  const float* emb     = (const float*)d_in[2];
  const float* w_ih    = (const float*)d_in[3];
  const float* w_hh    = (const float*)d_in[4];
  const float* b_ih    = (const float*)d_in[5];
  const float* b_hh    = (const float*)d_in[6];
  const float* w_out   = (const float*)d_in[7];
  const float* b_out   = (const float*)d_in[8];
  float*       outp    = (float*)d_out;

  // ring depth: largest power of two in [16, 512] that fits the workspace
  // (per-step footprint across all 8 groups is unchanged: 64 KiB).
  size_t avail = (ws_size > (size_t)XG_BYTES + 4096)
               ? ws_size - (size_t)XG_BYTES - 4096 : 0;
  int depth = 16;
  while (depth < 512 && ((size_t)depth * 2 * SLOT_TOT) <= avail) depth <<= 1;

  char* ws = (char*)d_ws;
  ushort_t* xg   = (ushort_t*)ws;                                  // 100,663,296 B
  char*     ring = ws + XG_BYTES;                                  // depth*65,536 B
  int*      prog = (int*)(ws + XG_BYTES + (size_t)depth * SLOT_TOT);

  gru_init<<<depth * 16, 256, 0, stream>>>((uintx4*)ring, prog);
  dim3 g1(SEQL, G3 / 64);
  gru_xgates<<<g1, 256, 0, stream>>>(seq, emb, w_ih, b_ih, xg);
  gru_rec<<<NGRP * NSLC, 256, 0, stream>>>(xg, w_hh, b_hh, lengths, ring, prog, depth);
  gru_out<<<BATCH, 64, 0, stream>>>(ring, lengths, w_out, b_out, outp, depth);
}

// Round 2
// 3050.697 us; speedup vs baseline: 5.6595x; 5.6595x over previous
//
#include <hip/hip_runtime.h>

// ---------------------------------------------------------------------------
// SimpleGRU on MI355X (gfx950). Round 8: dual-ring XCD-local exchange.
//   Round-6 (PASS, 3.00ms): system-scope (sc0 sc1) sentinel ring, 5.5us/step.
//   Round-7 (PASS, 17.3ms): fast path broke because producers stored sc0 sc1
//     (SYSTEM scope writes AROUND the XCD L2) while consumers polled sc0 (L2)
//     -> stale sentinel line in L2 forever -> 24 wasted rounds + 256-block
//     system-scope escalation storm every step (33us/step).
//   Fix: producer publishes TWICE per chunk: (1) sc0 store into the group's
//   FAST ring -> lands in the shared per-XCD L2, updating the polled line in
//   place; (2) sc0 sc1 store into the TRUTH ring -> L3 authoritative. Consumer
//   polls fast ring with sc0 (L2 round trip, ~100s ns); after 32 failed rounds
//   escalates to the truth ring with the round-6-proven sc0 sc1 protocol, and
//   after 10 escalated steps STICKY-downgrades to truth-only (worst case ==
//   round 6). If the dispatch is not 32 blocks per XCD, unanimous fallback to
//   LITERAL round 6: blocks ticket<32 run the 64-batch variant, rest retire.
// ws: xg bf16 [512][1536][64] (100,663,296 B) | truth [depth][64][512] f16
//     (depth*65,536 B) | fast [8][depth][8][512] f16 (depth*65,536 B) |
//     prog int[512]
// ---------------------------------------------------------------------------

typedef unsigned short ushort_t;
typedef short short8      __attribute__((ext_vector_type(8)));
typedef float floatx4     __attribute__((ext_vector_type(4)));
typedef unsigned int uintx4 __attribute__((ext_vector_type(4)));
typedef unsigned short ushort4v __attribute__((ext_vector_type(4)));
typedef _Float16 half8    __attribute__((ext_vector_type(8)));

#define SEQL 512
#define BATCH 64
#define EMBD 256
#define HID 512
#define G3 1536
#define NOUT 5
#define NGRP 8                     // one group per XCD (fast mode)
#define GRPB 8                     // batches per group (fast mode)
#define GSLOT 8192                 // fast ring slot: 8 x 512 x 2B
#define TSLOT 65536                // truth ring slot: 64 x 512 x 2B
#define RING2 131072               // truth + fast bytes per depth unit
#define XG_BYTES 100663296
#define FAST_TRIES 32
#define ESC_LIMIT 10

__device__ __forceinline__ float bf2f(ushort_t v){
  union { unsigned u; float f; } x; x.u = ((unsigned)v) << 16; return x.f;
}
__device__ __forceinline__ ushort_t f2bf(float f){
  unsigned u = __float_as_uint(f);
  return (ushort_t)((u + 0x7FFFu + ((u >> 16) & 1u)) >> 16);
}
__device__ __forceinline__ float sigm(float x){
  x = fminf(fmaxf(x, -20.f), 20.f);
  return 1.f / (1.f + __expf(-x));
}
__device__ __forceinline__ float tanh_c(float x){
  x = fminf(fmaxf(x, -10.f), 10.f);
  float e = __expf(2.f * x);
  return (e - 1.f) / (e + 1.f);
}
__device__ __forceinline__ bool has_sent(half8 v){
  union { half8 h; unsigned u[4]; } x; x.h = v;
  bool b = false;
  #pragma unroll
  for (int i = 0; i < 4; ++i){
    b |= ((x.u[i] & 0xFFFFu) == 0xFFFFu);
    b |= ((x.u[i] >> 16) == 0xFFFFu);
  }
  return b;
}

// --- K0: sentinel-fill both rings at SYSTEM scope (no dirty L2 lines left
//     behind -> no stale-eviction hazard); zero prog[512]. ---
__global__ __launch_bounds__(256) void gru_init(char* __restrict__ rings,
                                                int* __restrict__ prog){
  size_t i = ((size_t)blockIdx.x * 256 + threadIdx.x) * 16;
  uintx4 s = {0xFFFFFFFFu, 0xFFFFFFFFu, 0xFFFFFFFFu, 0xFFFFFFFFu};
  const char* p = rings + i;
  asm volatile("global_store_dwordx4 %0, %1, off sc0 sc1" :: "v"(p), "v"(s) : "memory");
  if (blockIdx.x == 0){
    int z = 0;
    asm volatile("global_store_dword %0, %1, off sc0 sc1"
                 :: "v"(prog + threadIdx.x), "v"(z) : "memory");
    asm volatile("global_store_dword %0, %1, off sc0 sc1"
                 :: "v"(prog + 256 + threadIdx.x), "v"(z) : "memory");
  }
}

// --- K1: x_gates = emb[seq] @ w_ih^T + b_ih, bf16, layout [s][1536][64] ---
#define LDSIDX2(row, chunk) (((row) << 7) + ((((chunk) ^ ((row) & 7))) << 3))
__global__ __launch_bounds__(256) void gru_xgates(
    const int* __restrict__ seq, const float* __restrict__ emb,
    const float* __restrict__ w_ih, const float* __restrict__ b_ih,
    ushort_t* __restrict__ xg)
{
  __shared__ __align__(16) short lA[64 * 128];
  __shared__ __align__(16) short lB[64 * 128];
  const int tid   = threadIdx.x;
  const int sIdx  = blockIdx.x;
  const int nBase = blockIdx.y * 64;
  const int w    = tid >> 6;
  const int l    = tid & 63;
  const int l15  = l & 15;
  const int quad = l >> 4;
  floatx4 acc[4] = {};

  #pragma unroll
  for (int kp = 0; kp < 2; ++kp){
    __syncthreads();
    #pragma unroll
    for (int i = 0; i < 4; ++i){
      int lin = i * 256 + tid;
      int row = lin >> 4;
      int kc  = lin & 15;
      int kbase = kp * 128 + kc * 8;
      int token = seq[(sIdx << 6) + row];
      const float* srcA = emb  + (size_t)token * EMBD + kbase;
      const float* srcB = w_ih + (size_t)(nBase + row) * EMBD + kbase;
      floatx4 a0 = *(const floatx4*)(srcA);
      floatx4 a1 = *(const floatx4*)(srcA + 4);
      floatx4 b0 = *(const floatx4*)(srcB);
      floatx4 b1 = *(const floatx4*)(srcB + 4);
      short8 pa, pb;
      #pragma unroll
      for (int j = 0; j < 4; ++j){
        pa[j]     = (short)f2bf(a0[j]);
        pa[j + 4] = (short)f2bf(a1[j]);
        pb[j]     = (short)f2bf(b0[j]);
        pb[j + 4] = (short)f2bf(b1[j]);
      }
      *(short8*)&lA[LDSIDX2(row, kc)] = pa;
      *(short8*)&lB[LDSIDX2(row, kc)] = pb;
    }
    __syncthreads();
    #pragma unroll
    for (int kc = 0; kc < 4; ++kc){
      int chunk = kc * 4 + quad;
      short8 a = *(const short8*)&lA[LDSIDX2(w * 16 + l15, chunk)];
      #pragma unroll
      for (int s = 0; s < 4; ++s){
        short8 bf = *(const short8*)&lB[LDSIDX2(s * 16 + l15, chunk)];
        acc[s] = __builtin_amdgcn_mfma_f32_16x16x32_bf16(a, bf, acc[s], 0, 0, 0);
      }
    }
  }
  #pragma unroll
  for (int s = 0; s < 4; ++s){
    int g = nBase + s * 16 + l15;
    float bias = b_ih[g];
    ushort4v pk;
    #pragma unroll
    for (int r = 0; r < 4; ++r) pk[r] = f2bf(acc[s][r] + bias);
    *(ushort4v*)(xg + ((size_t)sIdx * G3 + g) * BATCH + (w * 16 + quad * 4)) = pk;
  }
}

// --- K2: recurrence. 256 blocks x 256 threads. Fast mode: 8 XCD-local groups,
//     wave0 only, dual-ring publish. Fallback: literal round-6 (32 blocks). ---
__global__ __launch_bounds__(256, 1) void gru_rec(
    const ushort_t* __restrict__ xg, const float* __restrict__ whh,
    const float* __restrict__ bhh, const int* __restrict__ lengths,
    char* __restrict__ truth, char* __restrict__ fastr,
    int* __restrict__ prog, int depth)
{
  __shared__ __align__(16) _Float16 wlds[48 * 64 * 8];   // 49,152 B (B-frags)
  __shared__ __align__(16) _Float16 hscr[4 * 256];       //  2,048 B (repack)
  __shared__ int s_grp, s_slc, s_fast;
  const int tid  = threadIdx.x;
  const int w    = tid >> 6;
  const int l    = tid & 63;
  const int l15  = l & 15;
  const int quad = l >> 4;

  // ---- rendezvous + XCD-affinity group formation ----
  int* regs = prog + 384;              // [0]=gcount, [1..8]=per-XCD counts
  if (tid == 0){
    unsigned xcd;
    asm volatile("s_getreg_b32 %0, hwreg(HW_REG_XCC_ID)" : "=s"(xcd));
    xcd &= 7u;
    int myx = atomicAdd(&regs[1 + xcd], 1);
    asm volatile("s_waitcnt vmcnt(0)" ::: "memory");  // xcd count visible first
    int gt = atomicAdd(&regs[0], 1);
    int v;
    do {
      asm volatile("s_sleep 1" ::: "memory");
      asm volatile("global_load_dword %0, %1, off sc0 sc1\n\t"
                   "s_waitcnt vmcnt(0)"
                   : "=v"(v) : "v"(&regs[0]) : "memory");
    } while (v < 256);
    int ok = 1;
    #pragma unroll
    for (int x = 0; x < 8; ++x){
      int c;
      asm volatile("global_load_dword %0, %1, off sc0 sc1\n\t"
                   "s_waitcnt vmcnt(0)"
                   : "=v"(c) : "v"(&regs[1 + x]) : "memory");
      ok &= (c == 32);
    }
    s_fast = ok;
    s_grp  = ok ? (int)xcd : 0;
    s_slc  = ok ? (myx & 31) : gt;
  }
  __syncthreads();
  const int fast = s_fast;
  const int grp  = s_grp;
  const int g0   = s_slc;
  if (!fast && g0 >= 32) return;       // fallback: only 32 blocks participate
  const int g = g0 & 31;               // hidden slice [g*16, g*16+16)
  const int j = g * 16 + l15;          // this lane's hidden unit

  // ---- setup: 48 W_hh rows f32->f16 into B-frag LDS (all 4 waves) ----
  #pragma unroll
  for (int i = 0; i < 12; ++i){
    int p  = i * 4 + w;                 // 0..47
    int G  = p >> 4;                    // gate (0=r,1=z,2=n)
    int ks = p & 15;                    // K-step
    const float* src = whh + (size_t)(G * HID + j) * HID + ks * 32 + quad * 8;
    floatx4 f0 = *(const floatx4*)(src);
    floatx4 f1 = *(const floatx4*)(src + 4);
    half8 hv;
    #pragma unroll
    for (int q = 0; q < 4; ++q){ hv[q] = (_Float16)f0[q]; hv[q + 4] = (_Float16)f1[q]; }
    *(half8*)&wlds[((size_t)p * 64 + l) * 8] = hv;
  }
  __syncthreads();
  if (fast && tid >= 64) return;       // fast mode: wave 0 runs alone

  char* fastb = fastr + (size_t)grp * depth * GSLOT;
  const int locb = fast ? ((quad & 1) * 4) : (quad * 4);  // wave-local batch base
  const int gb   = fast ? (grp * GRPB + locb) : (w * 16 + locb);  // global batch
  const int arow = l15 & 7;                                // fast ring A-row
  const int trow = fast ? (grp * GRPB + (l15 & 7)) : (w * 16 + l15); // truth row
  const float bhR = bhh[j], bhZ = bhh[HID + j], bhN = bhh[2 * HID + j];
  int   len[4];
  float h[4];
  #pragma unroll
  for (int r = 0; r < 4; ++r){ len[r] = lengths[gb + r]; h[r] = 0.f; }
  const int Lmax  = lengths[0];        // global max: all blocks run to Lmax
  const int mask  = depth - 1;
  const bool reuse = (depth < Lmax);
  int cmin = 0;
  int esc = 0;
  int fastpoll = fast;                 // sticky downgrade switch

  for (int t = 0; t < Lmax; ++t){
    // 0) ring-reuse guard (off critical path when depth >= Lmax)
    if (reuse && t >= depth){
      int target = t - depth + 2;
      if (cmin < target){
        int tgt2 = target + 4;          // slack; publishes every 8 guarantee progress
        if (fast){
          const int* pp = prog + 128 + grp * 32 + (l & 31);
          while (true){
            int p0;
            asm volatile("global_load_dword %0, %1, off sc0 sc1\n\t"
                         "s_waitcnt vmcnt(0)"
                         : "=v"(p0) : "v"(pp) : "memory");
            if (__all(p0 >= tgt2)) break;
            __builtin_amdgcn_s_sleep(2);
          }
        } else {
          while (true){
            int p0, p1;
            asm volatile("global_load_dword %0, %2, off sc0 sc1\n\t"
                         "global_load_dword %1, %3, off sc0 sc1\n\t"
                         "s_waitcnt vmcnt(0)"
                         : "=v"(p0), "=v"(p1) : "v"(prog + l), "v"(prog + 64 + l)
                         : "memory");
            if (__all(p0 >= tgt2 && p1 >= tgt2)) break;
            __builtin_amdgcn_s_sleep(2);
          }
        }
        cmin = tgt2;
      }
    }

    // 1) xg prefetch (independent of h)
    const ushort_t* xt = xg + (size_t)t * G3 * BATCH;
    ushort4v xR = __builtin_nontemporal_load(
        (const ushort4v*)(xt + (size_t)(          j) * BATCH + gb));
    ushort4v xZ = __builtin_nontemporal_load(
        (const ushort4v*)(xt + (size_t)(HID     + j) * BATCH + gb));
    ushort4v xN = __builtin_nontemporal_load(
        (const ushort4v*)(xt + (size_t)(2 * HID + j) * BATCH + gb));

    // 2) consume h(t-1): poll fast ring at sc0 (XCD L2); escalate to the
    //    truth ring at sc0 sc1 after FAST_TRIES; sticky-downgrade after
    //    ESC_LIMIT escalated steps.
    floatx4 aR = {0.f,0.f,0.f,0.f}, aZ = {0.f,0.f,0.f,0.f}, aN = {0.f,0.f,0.f,0.f};
    if (t > 0){
      const int slotp = (t - 1) & mask;
      const char* rowf = fastb + (size_t)slotp * GSLOT
                       + (size_t)arow * 1024 + quad * 16;
      const char* rowt = truth + (size_t)slotp * TSLOT
                       + (size_t)trow * 1024 + quad * 16;
      half8 aF[16];
      int tries = fastpoll ? FAST_TRIES : 0;
      int trounds = 0;
      while (true){
        if (tries > 0){
          --tries;
          #pragma unroll
          for (int ks = 0; ks < 16; ++ks){
            const char* pa = rowf + ks * 64;
            asm volatile("global_load_dwordx4 %0, %1, off sc0"
                         : "=v"(aF[ks]) : "v"(pa) : "memory");
          }
        } else {
          if (trounds++) __builtin_amdgcn_s_sleep(2);   // backoff vs fabric storm
          #pragma unroll
          for (int ks = 0; ks < 16; ++ks){
            const char* pa = rowt + ks * 64;
            asm volatile("global_load_dwordx4 %0, %1, off sc0 sc1"
                         : "=v"(aF[ks]) : "v"(pa) : "memory");
          }
        }
        asm volatile("s_waitcnt vmcnt(0)"
                     : "+v"(aF[0]),  "+v"(aF[1]),  "+v"(aF[2]),  "+v"(aF[3]),
                       "+v"(aF[4]),  "+v"(aF[5]),  "+v"(aF[6]),  "+v"(aF[7]),
                       "+v"(aF[8]),  "+v"(aF[9]),  "+v"(aF[10]), "+v"(aF[11]),
                       "+v"(aF[12]), "+v"(aF[13]), "+v"(aF[14]), "+v"(aF[15])
                     :: "memory");
        bool bad = false;
        #pragma unroll
        for (int ks = 0; ks < 16; ++ks) bad |= has_sent(aF[ks]);
        if (!__any(bad)) break;
      }
      if (fastpoll && trounds > 0){      // this step needed escalation
        if (++esc >= ESC_LIMIT) fastpoll = 0;
      }
      #pragma unroll
      for (int ks = 0; ks < 16; ++ks){
        half8 a  = aF[ks];
        half8 b0 = *(const half8*)&wlds[((size_t)(0 * 16 + ks) * 64 + l) * 8];
        half8 b1 = *(const half8*)&wlds[((size_t)(1 * 16 + ks) * 64 + l) * 8];
        half8 b2 = *(const half8*)&wlds[((size_t)(2 * 16 + ks) * 64 + l) * 8];
        aR = __builtin_amdgcn_mfma_f32_16x16x32_f16(a, b0, aR, 0, 0, 0);
        aZ = __builtin_amdgcn_mfma_f32_16x16x32_f16(a, b1, aZ, 0, 0, 0);
        aN = __builtin_amdgcn_mfma_f32_16x16x32_f16(a, b2, aN, 0, 0, 0);
      }
      // restore sentinels on consumed chunks so slots can be reused
      if (reuse){
        uintx4 sv = {0xFFFFFFFFu, 0xFFFFFFFFu, 0xFFFFFFFFu, 0xFFFFFFFFu};
        if (fast){
          if (l15 < 8){
            #pragma unroll
            for (int ks = 0; ks < 16; ++ks){
              const char* pf = rowf + ks * 64;
              const char* pt = rowt + ks * 64;
              asm volatile("global_store_dwordx4 %0, %1, off sc0"
                           :: "v"(pf), "v"(sv) : "memory");
              asm volatile("global_store_dwordx4 %0, %1, off sc0 sc1"
                           :: "v"(pt), "v"(sv) : "memory");
            }
          }
        } else {
          #pragma unroll
          for (int ks = 0; ks < 16; ++ks){
            const char* pt = rowt + ks * 64;
            asm volatile("global_store_dwordx4 %0, %1, off sc0 sc1"
                         :: "v"(pt), "v"(sv) : "memory");
          }
        }
      }
    }

    // 3) gates + h update (f32 carry); mirrored quads duplicate harmlessly
    #pragma unroll
    for (int r = 0; r < 4; ++r){
      float rr = sigm(bf2f(xR[r]) + aR[r] + bhR);
      float zz = sigm(bf2f(xZ[r]) + aZ[r] + bhZ);
      float nn = tanh_c(bf2f(xN[r]) + rr * (aN[r] + bhN));
      float hn = (1.f - zz) * nn + zz * h[r];
      h[r] = (t < len[r]) ? hn : h[r];
    }

    // 4) intra-wave repack via LDS, then publish h(t): fast ring first (sc0,
    //    lands in the group's L2), then truth ring (sc0 sc1, L3 authoritative)
    _Float16* scr = hscr + w * 256;
    if (!fast || quad < 2){
      #pragma unroll
      for (int r = 0; r < 4; ++r) scr[(locb + r) * 16 + l15] = (_Float16)h[r];
    }
    asm volatile("s_waitcnt lgkmcnt(0)" ::: "memory");   // wave-local DS order
    {
      const int pubN = fast ? 16 : 32;
      if (l < pubN){
        int bl = l >> 1;                // local batch
        int hc = l & 1;                 // which 8-wide half of the 16-slice
        half8 ch = *(const half8*)&scr[bl * 16 + hc * 8];
        int gbatch = fast ? (grp * GRPB + bl) : (w * 16 + bl);
        if (fast){
          const char* df = fastb + (size_t)(t & mask) * GSLOT
                         + (size_t)bl * 1024 + (size_t)g * 32 + (size_t)hc * 16;
          asm volatile("global_store_dwordx4 %0, %1, off sc0"
                       :: "v"(df), "v"(ch) : "memory");
        }
        const char* dt = truth + (size_t)(t & mask) * TSLOT
                       + (size_t)gbatch * 1024 + (size_t)g * 32 + (size_t)hc * 16;
        asm volatile("global_store_dwordx4 %0, %1, off sc0 sc1"
                     :: "v"(dt), "v"(ch) : "memory");
      }
    }

    // 5) coarse progress publish (reuse mode only), ordered after restores
    if (reuse && ((t & 7) == 7)){
      asm volatile("s_waitcnt vmcnt(0)" ::: "memory");
      if (l == 0){
        int pv = t + 1;
        const int* pp = fast ? (prog + 128 + grp * 32 + g) : (prog + w * 32 + g);
        asm volatile("global_store_dword %0, %1, off sc0 sc1"
                     :: "v"(pp), "v"(pv) : "memory");
      }
    }
  }
}

// --- K3: logits + log_softmax from truth slot (Lmax-1). 64 blocks x 64. ---
__global__ __launch_bounds__(64) void gru_out(
    const char* __restrict__ truth, const int* __restrict__ lengths,
    const float* __restrict__ wout, const float* __restrict__ bout,
    float* __restrict__ out, int depth)
{
  const int b = blockIdx.x, l = threadIdx.x;
  const int Lmax = lengths[0];
  const _Float16* h = (const _Float16*)(truth
      + (size_t)((Lmax - 1) & (depth - 1)) * TSLOT + (size_t)b * 1024);
  half8 hv = *(const half8*)(h + l * 8);
  float p[NOUT];
  #pragma unroll
  for (int o = 0; o < NOUT; ++o){
    const float* wr = wout + o * HID + l * 8;
    float a = 0.f;
    #pragma unroll
    for (int i = 0; i < 8; ++i) a += wr[i] * (float)hv[i];
    #pragma unroll
    for (int d = 32; d >= 1; d >>= 1) a += __shfl_down(a, d, 64);
    p[o] = a;
  }
  if (l == 0){
    float lg[NOUT], m = -1e30f;
    #pragma unroll
    for (int o = 0; o < NOUT; ++o){
      float v = p[o] + bout[o];
      if (!(v == v)) v = -1.0f;
      lg[o] = v; m = fmaxf(m, v);
    }
    float ssum = 0.f;
    #pragma unroll
    for (int o = 0; o < NOUT; ++o) ssum += __expf(lg[o] - m);
    float ls = __logf(ssum);
    #pragma unroll
    for (int o = 0; o < NOUT; ++o) out[b * NOUT + o] = lg[o] - m - ls;
  }
}

extern "C" void kernel_launch(void* const* d_in, const int* in_sizes, int n_in,
                              void* d_out, int out_size, void* d_ws, size_t ws_size,
                              hipStream_t stream) {
  (void)in_sizes; (void)n_in; (void)out_size;
  const int*   seq     = (const int*)d_in[0];
  const int*   lengths = (const int*)d_in[1];
  const float* emb     = (const float*)d_in[2];
  const float* w_ih    = (const float*)d_in[3];
  const float* w_hh    = (const float*)d_in[4];
  const float* b_ih    = (const float*)d_in[5];
  const float* b_hh    = (const float*)d_in[6];
  const float* w_out   = (const float*)d_in[7];
  const float* b_out   = (const float*)d_in[8];
  float*       outp    = (float*)d_out;

  // ring depth: largest power of two in [16, 512] such that BOTH rings
  // (depth * 128 KiB total) + prog fit the workspace after xg.
  size_t avail = (ws_size > (size_t)XG_BYTES + 8192)
               ? ws_size - (size_t)XG_BYTES - 8192 : 0;
  int depth = 16;
  while (depth < 512 && ((size_t)(depth << 1) * RING2 + 2048) <= avail) depth <<= 1;

  char* ws = (char*)d_ws;
  ushort_t* xg    = (ushort_t*)ws;                                 // 100,663,296 B
  char*     truth = ws + XG_BYTES;                                 // depth*65,536 B
  char*     fastr = truth + (size_t)depth * TSLOT;                 // depth*65,536 B
  int*      prog  = (int*)(fastr + (size_t)depth * TSLOT);         // 512 ints

  gru_init<<<depth * 32, 256, 0, stream>>>(truth, prog);
  dim3 g1(SEQL, G3 / 64);
  gru_xgates<<<g1, 256, 0, stream>>>(seq, emb, w_ih, b_ih, xg);
  gru_rec<<<256, 256, 0, stream>>>(xg, w_hh, b_hh, lengths, truth, fastr, prog, depth);
  gru_out<<<BATCH, 64, 0, stream>>>(truth, lengths, w_out, b_out, outp, depth);
}

// Round 3
// 2126.073 us; speedup vs baseline: 8.1208x; 1.4349x over previous
//
#include <hip/hip_runtime.h>

// ---------------------------------------------------------------------------
// SimpleGRU on MI355X (gfx950). Round 9: counter-released XCD-local exchange.
//   Round-6 (PASS, 3.00ms): system-scope sentinel-POLLED ring, 5.5us/step.
//   Round-8 (PASS, 2.9ms): dual-ring sc0 fast path engaged (WRITE 2x proves
//     it) but bought nothing -> polling the DATA is the bug class: the
//     consumer's speculative polls plant a stale line ahead of the store
//     and/or the 256-wave poll storm inflates every fabric RT ~10x.
//   Now: detection and data are SEPARATE. Producer: fast-ring data sc0 ->
//   s_waitcnt vmcnt(0) (= data complete in own XCD L2) -> ONE
//   global_atomic_add ctr[grp][slot] (device-coherent) -> truth-ring sc0 sc1
//   fire-and-forget. Consumer: spin on the single 4B counter (sc0 sc1 +
//   s_sleep backoff; 32 pollers on one line), then ONE-SHOT sc0 read of data
//   from the shared L2 -- the data address is never touched before release,
//   so no stale line can exist; the completed sc0 store is in the same L2.
//   Safety: sentinel-check the one-shot read; any sentinel -> self-syncing
//   truth-ring sentinel poll (round-6 semantics); sticky downgrade after 8
//   bad steps -> ctr-gate + truth read. Non-32/XCD dispatch or ring reuse ->
//   literal round-6 fallback (proven 2.9ms bound).
// ws: xg bf16 [512][1536][64] (100,663,296 B) | truth [depth][64][512] f16 |
//     fast [8][depth][8][512] f16 | prog int[512] | ctr int[8][512]
// ---------------------------------------------------------------------------

typedef unsigned short ushort_t;
typedef short short8      __attribute__((ext_vector_type(8)));
typedef float floatx4     __attribute__((ext_vector_type(4)));
typedef unsigned int uintx4 __attribute__((ext_vector_type(4)));
typedef unsigned short ushort4v __attribute__((ext_vector_type(4)));
typedef _Float16 half8    __attribute__((ext_vector_type(8)));

#define SEQL 512
#define BATCH 64
#define EMBD 256
#define HID 512
#define G3 1536
#define NOUT 5
#define NGRP 8                     // one group per XCD (fast mode)
#define GRPB 8                     // batches per group (fast mode)
#define GSLOT 8192                 // fast ring slot: 8 x 512 x 2B
#define TSLOT 65536                // truth ring slot: 64 x 512 x 2B
#define RING2 131072               // truth + fast bytes per depth unit
#define XG_BYTES 100663296
#define PROGN 512
#define CTRN (NGRP * 512)
#define ZERON (PROGN + CTRN)       // 4608 ints zeroed by init
#define BAD_LIMIT 8

__device__ __forceinline__ float bf2f(ushort_t v){
  union { unsigned u; float f; } x; x.u = ((unsigned)v) << 16; return x.f;
}
__device__ __forceinline__ ushort_t f2bf(float f){
  unsigned u = __float_as_uint(f);
  return (ushort_t)((u + 0x7FFFu + ((u >> 16) & 1u)) >> 16);
}
__device__ __forceinline__ float sigm(float x){
  x = fminf(fmaxf(x, -20.f), 20.f);
  return 1.f / (1.f + __expf(-x));
}
__device__ __forceinline__ float tanh_c(float x){
  x = fminf(fmaxf(x, -10.f), 10.f);
  float e = __expf(2.f * x);
  return (e - 1.f) / (e + 1.f);
}
__device__ __forceinline__ bool has_sent(half8 v){
  union { half8 h; unsigned u[4]; } x; x.h = v;
  bool b = false;
  #pragma unroll
  for (int i = 0; i < 4; ++i){
    b |= ((x.u[i] & 0xFFFFu) == 0xFFFFu);
    b |= ((x.u[i] >> 16) == 0xFFFFu);
  }
  return b;
}

// --- K0: sentinel-fill both rings at SYSTEM scope; zero prog+ctr. ---
__global__ __launch_bounds__(256) void gru_init(char* __restrict__ rings,
                                                int* __restrict__ prog){
  size_t i = ((size_t)blockIdx.x * 256 + threadIdx.x) * 16;
  uintx4 s = {0xFFFFFFFFu, 0xFFFFFFFFu, 0xFFFFFFFFu, 0xFFFFFFFFu};
  const char* p = rings + i;
  asm volatile("global_store_dwordx4 %0, %1, off sc0 sc1" :: "v"(p), "v"(s) : "memory");
  if (blockIdx.x == 0){
    int z = 0;
    for (int k = threadIdx.x; k < ZERON; k += 256){
      asm volatile("global_store_dword %0, %1, off sc0 sc1"
                   :: "v"(prog + k), "v"(z) : "memory");
    }
  }
}

// --- K1: x_gates = emb[seq] @ w_ih^T + b_ih, bf16, layout [s][1536][64] ---
#define LDSIDX2(row, chunk) (((row) << 7) + ((((chunk) ^ ((row) & 7))) << 3))
__global__ __launch_bounds__(256) void gru_xgates(
    const int* __restrict__ seq, const float* __restrict__ emb,
    const float* __restrict__ w_ih, const float* __restrict__ b_ih,
    ushort_t* __restrict__ xg)
{
  __shared__ __align__(16) short lA[64 * 128];
  __shared__ __align__(16) short lB[64 * 128];
  const int tid   = threadIdx.x;
  const int sIdx  = blockIdx.x;
  const int nBase = blockIdx.y * 64;
  const int w    = tid >> 6;
  const int l    = tid & 63;
  const int l15  = l & 15;
  const int quad = l >> 4;
  floatx4 acc[4] = {};

  #pragma unroll
  for (int kp = 0; kp < 2; ++kp){
    __syncthreads();
    #pragma unroll
    for (int i = 0; i < 4; ++i){
      int lin = i * 256 + tid;
      int row = lin >> 4;
      int kc  = lin & 15;
      int kbase = kp * 128 + kc * 8;
      int token = seq[(sIdx << 6) + row];
      const float* srcA = emb  + (size_t)token * EMBD + kbase;
      const float* srcB = w_ih + (size_t)(nBase + row) * EMBD + kbase;
      floatx4 a0 = *(const floatx4*)(srcA);
      floatx4 a1 = *(const floatx4*)(srcA + 4);
      floatx4 b0 = *(const floatx4*)(srcB);
      floatx4 b1 = *(const floatx4*)(srcB + 4);
      short8 pa, pb;
      #pragma unroll
      for (int j = 0; j < 4; ++j){
        pa[j]     = (short)f2bf(a0[j]);
        pa[j + 4] = (short)f2bf(a1[j]);
        pb[j]     = (short)f2bf(b0[j]);
        pb[j + 4] = (short)f2bf(b1[j]);
      }
      *(short8*)&lA[LDSIDX2(row, kc)] = pa;
      *(short8*)&lB[LDSIDX2(row, kc)] = pb;
    }
    __syncthreads();
    #pragma unroll
    for (int kc = 0; kc < 4; ++kc){
      int chunk = kc * 4 + quad;
      short8 a = *(const short8*)&lA[LDSIDX2(w * 16 + l15, chunk)];
      #pragma unroll
      for (int s = 0; s < 4; ++s){
        short8 bf = *(const short8*)&lB[LDSIDX2(s * 16 + l15, chunk)];
        acc[s] = __builtin_amdgcn_mfma_f32_16x16x32_bf16(a, bf, acc[s], 0, 0, 0);
      }
    }
  }
  #pragma unroll
  for (int s = 0; s < 4; ++s){
    int g = nBase + s * 16 + l15;
    float bias = b_ih[g];
    ushort4v pk;
    #pragma unroll
    for (int r = 0; r < 4; ++r) pk[r] = f2bf(acc[s][r] + bias);
    *(ushort4v*)(xg + ((size_t)sIdx * G3 + g) * BATCH + (w * 16 + quad * 4)) = pk;
  }
}

// --- K2: recurrence. 256 blocks x 256 threads. ---
__global__ __launch_bounds__(256, 1) void gru_rec(
    const ushort_t* __restrict__ xg, const float* __restrict__ whh,
    const float* __restrict__ bhh, const int* __restrict__ lengths,
    char* __restrict__ truth, char* __restrict__ fastr,
    int* __restrict__ prog, int depth)
{
  __shared__ __align__(16) _Float16 wlds[48 * 64 * 8];   // 49,152 B (B-frags)
  __shared__ __align__(16) _Float16 hscr[4 * 256];       //  2,048 B (repack)
  __shared__ int s_grp, s_slc, s_fast;
  const int tid  = threadIdx.x;
  const int w    = tid >> 6;
  const int l    = tid & 63;
  const int l15  = l & 15;
  const int quad = l >> 4;
  int* ctr = prog + PROGN;             // [NGRP][512] monotonic step counters

  // ---- rendezvous + XCD-affinity group formation ----
  int* regs = prog + 384;              // [0]=gcount, [1..8]=per-XCD counts
  if (tid == 0){
    unsigned xcd;
    asm volatile("s_getreg_b32 %0, hwreg(HW_REG_XCC_ID)" : "=s"(xcd));
    xcd &= 7u;
    int myx = atomicAdd(&regs[1 + xcd], 1);
    asm volatile("s_waitcnt vmcnt(0)" ::: "memory");  // xcd count visible first
    int gt = atomicAdd(&regs[0], 1);
    int v;
    do {
      asm volatile("s_sleep 1" ::: "memory");
      asm volatile("global_load_dword %0, %1, off sc0 sc1\n\t"
                   "s_waitcnt vmcnt(0)"
                   : "=v"(v) : "v"(&regs[0]) : "memory");
    } while (v < 256);
    int ok = 1;
    #pragma unroll
    for (int x = 0; x < 8; ++x){
      int c;
      asm volatile("global_load_dword %0, %1, off sc0 sc1\n\t"
                   "s_waitcnt vmcnt(0)"
                   : "=v"(c) : "v"(&regs[1 + x]) : "memory");
      ok &= (c == 32);
    }
    s_fast = ok;
    s_grp  = ok ? (int)xcd : 0;
    s_slc  = ok ? (myx & 31) : gt;
  }
  __syncthreads();
  const int fast = s_fast;
  const int grp  = s_grp;
  const int g0   = s_slc;
  if (!fast && g0 >= 32) return;       // fallback: only 32 blocks participate
  const int g = g0 & 31;               // hidden slice [g*16, g*16+16)
  const int j = g * 16 + l15;          // this lane's hidden unit

  // ---- setup: 48 W_hh rows f32->f16 into B-frag LDS (all 4 waves) ----
  #pragma unroll
  for (int i = 0; i < 12; ++i){
    int p  = i * 4 + w;                 // 0..47
    int G  = p >> 4;                    // gate (0=r,1=z,2=n)
    int ks = p & 15;                    // K-step
    const float* src = whh + (size_t)(G * HID + j) * HID + ks * 32 + quad * 8;
    floatx4 f0 = *(const floatx4*)(src);
    floatx4 f1 = *(const floatx4*)(src + 4);
    half8 hv;
    #pragma unroll
    for (int q = 0; q < 4; ++q){ hv[q] = (_Float16)f0[q]; hv[q + 4] = (_Float16)f1[q]; }
    *(half8*)&wlds[((size_t)p * 64 + l) * 8] = hv;
  }
  __syncthreads();
  if (fast && tid >= 64) return;       // fast mode: wave 0 runs alone

  char* fastb = fastr + (size_t)grp * depth * GSLOT;
  const int locb = fast ? ((quad & 1) * 4) : (quad * 4);  // wave-local batch base
  const int gb   = fast ? (grp * GRPB + locb) : (w * 16 + locb);  // global batch
  const int arow = l15 & 7;                                // fast ring A-row
  const int trow = fast ? (grp * GRPB + (l15 & 7)) : (w * 16 + l15); // truth row
  const float bhR = bhh[j], bhZ = bhh[HID + j], bhN = bhh[2 * HID + j];
  int   len[4];
  float h[4];
  #pragma unroll
  for (int r = 0; r < 4; ++r){ len[r] = lengths[gb + r]; h[r] = 0.f; }
  const int Lmax  = lengths[0];        // global max: all blocks run to Lmax
  const int mask  = depth - 1;
  const bool reuse = (depth < Lmax);
  const int ctrmode = fast && !reuse;  // counter-released L2 exchange
  int cmin = 0;
  int badcnt = 0;
  int fastpoll = ctrmode;              // sticky downgrade switch (data path)

  for (int t = 0; t < Lmax; ++t){
    // 0) ring-reuse guard (legacy modes only; dead when depth >= Lmax)
    if (reuse && t >= depth){
      int target = t - depth + 2;
      if (cmin < target){
        int tgt2 = target + 4;
        if (fast){
          const int* pp = prog + 128 + grp * 32 + (l & 31);
          while (true){
            int p0;
            asm volatile("global_load_dword %0, %1, off sc0 sc1\n\t"
                         "s_waitcnt vmcnt(0)"
                         : "=v"(p0) : "v"(pp) : "memory");
            if (__all(p0 >= tgt2)) break;
            __builtin_amdgcn_s_sleep(2);
          }
        } else {
          while (true){
            int p0, p1;
            asm volatile("global_load_dword %0, %2, off sc0 sc1\n\t"
                         "global_load_dword %1, %3, off sc0 sc1\n\t"
                         "s_waitcnt vmcnt(0)"
                         : "=v"(p0), "=v"(p1) : "v"(prog + l), "v"(prog + 64 + l)
                         : "memory");
            if (__all(p0 >= tgt2 && p1 >= tgt2)) break;
            __builtin_amdgcn_s_sleep(2);
          }
        }
        cmin = tgt2;
      }
    }

    // 1) xg prefetch (independent of h)
    const ushort_t* xt = xg + (size_t)t * G3 * BATCH;
    ushort4v xR = __builtin_nontemporal_load(
        (const ushort4v*)(xt + (size_t)(          j) * BATCH + gb));
    ushort4v xZ = __builtin_nontemporal_load(
        (const ushort4v*)(xt + (size_t)(HID     + j) * BATCH + gb));
    ushort4v xN = __builtin_nontemporal_load(
        (const ushort4v*)(xt + (size_t)(2 * HID + j) * BATCH + gb));

    // 2) consume h(t-1)
    floatx4 aR = {0.f,0.f,0.f,0.f}, aZ = {0.f,0.f,0.f,0.f}, aN = {0.f,0.f,0.f,0.f};
    if (t > 0){
      const int slotp = (t - 1) & mask;
      const char* rowf = fastb + (size_t)slotp * GSLOT
                       + (size_t)arow * 1024 + quad * 16;
      const char* rowt = truth + (size_t)slotp * TSLOT
                       + (size_t)trow * 1024 + quad * 16;
      half8 aF[16];
      bool good = false;
      if (ctrmode){
        // 2a) counter gate: wait for all 32 producers' release
        const int* cp = ctr + ((grp << 9) | slotp);
        int cv;
        while (true){
          asm volatile("global_load_dword %0, %1, off sc0 sc1\n\t"
                       "s_waitcnt vmcnt(0)"
                       : "=v"(cv) : "v"(cp) : "memory");
          if (cv >= 32) break;
          __builtin_amdgcn_s_sleep(1);
        }
        // 2b) one-shot data read from the shared XCD L2 (first touch of
        //     this address by this block -> no stale line can exist)
        if (fastpoll){
          #pragma unroll
          for (int ks = 0; ks < 16; ++ks){
            const char* pa = rowf + ks * 64;
            asm volatile("global_load_dwordx4 %0, %1, off sc0"
                         : "=v"(aF[ks]) : "v"(pa) : "memory");
          }
          asm volatile("s_waitcnt vmcnt(0)"
                       : "+v"(aF[0]),  "+v"(aF[1]),  "+v"(aF[2]),  "+v"(aF[3]),
                         "+v"(aF[4]),  "+v"(aF[5]),  "+v"(aF[6]),  "+v"(aF[7]),
                         "+v"(aF[8]),  "+v"(aF[9]),  "+v"(aF[10]), "+v"(aF[11]),
                         "+v"(aF[12]), "+v"(aF[13]), "+v"(aF[14]), "+v"(aF[15])
                       :: "memory");
        bool bad = false;
          #pragma unroll
          for (int ks = 0; ks < 16; ++ks) bad |= has_sent(aF[ks]);
          good = !__any(bad);
          if (!good && ++badcnt >= BAD_LIMIT) fastpoll = 0;
        }
      }
      if (!good){
        // legacy / escalation: self-synchronizing sentinel poll on truth
        int rounds = 0;
        while (true){
          if (rounds++) __builtin_amdgcn_s_sleep(2);
          #pragma unroll
          for (int ks = 0; ks < 16; ++ks){
            const char* pa = rowt + ks * 64;
            asm volatile("global_load_dwordx4 %0, %1, off sc0 sc1"
                         : "=v"(aF[ks]) : "v"(pa) : "memory");
          }
          asm volatile("s_waitcnt vmcnt(0)"
                       : "+v"(aF[0]),  "+v"(aF[1]),  "+v"(aF[2]),  "+v"(aF[3]),
                         "+v"(aF[4]),  "+v"(aF[5]),  "+v"(aF[6]),  "+v"(aF[7]),
                         "+v"(aF[8]),  "+v"(aF[9]),  "+v"(aF[10]), "+v"(aF[11]),
                         "+v"(aF[12]), "+v"(aF[13]), "+v"(aF[14]), "+v"(aF[15])
                       :: "memory");
          bool bad = false;
          #pragma unroll
          for (int ks = 0; ks < 16; ++ks) bad |= has_sent(aF[ks]);
          if (!__any(bad)) break;
        }
      }
      #pragma unroll
      for (int ks = 0; ks < 16; ++ks){
        half8 a  = aF[ks];
        half8 b0 = *(const half8*)&wlds[((size_t)(0 * 16 + ks) * 64 + l) * 8];
        half8 b1 = *(const half8*)&wlds[((size_t)(1 * 16 + ks) * 64 + l) * 8];
        half8 b2 = *(const half8*)&wlds[((size_t)(2 * 16 + ks) * 64 + l) * 8];
        aR = __builtin_amdgcn_mfma_f32_16x16x32_f16(a, b0, aR, 0, 0, 0);
        aZ = __builtin_amdgcn_mfma_f32_16x16x32_f16(a, b1, aZ, 0, 0, 0);
        aN = __builtin_amdgcn_mfma_f32_16x16x32_f16(a, b2, aN, 0, 0, 0);
      }
      // restore sentinels on consumed truth chunks (legacy reuse only)
      if (reuse){
        uintx4 sv = {0xFFFFFFFFu, 0xFFFFFFFFu, 0xFFFFFFFFu, 0xFFFFFFFFu};
        if (!fast || l15 < 8){
          #pragma unroll
          for (int ks = 0; ks < 16; ++ks){
            const char* pt = rowt + ks * 64;
            asm volatile("global_store_dwordx4 %0, %1, off sc0 sc1"
                         :: "v"(pt), "v"(sv) : "memory");
          }
        }
      }
    }

    // 3) gates + h update (f32 carry); mirrored quads duplicate harmlessly
    #pragma unroll
    for (int r = 0; r < 4; ++r){
      float rr = sigm(bf2f(xR[r]) + aR[r] + bhR);
      float zz = sigm(bf2f(xZ[r]) + aZ[r] + bhZ);
      float nn = tanh_c(bf2f(xN[r]) + rr * (aN[r] + bhN));
      float hn = (1.f - zz) * nn + zz * h[r];
      h[r] = (t < len[r]) ? hn : h[r];
    }

    // 4) intra-wave repack via LDS, then publish h(t)
    _Float16* scr = hscr + w * 256;
    if (!fast || quad < 2){
      #pragma unroll
      for (int r = 0; r < 4; ++r) scr[(locb + r) * 16 + l15] = (_Float16)h[r];
    }
    asm volatile("s_waitcnt lgkmcnt(0)" ::: "memory");   // wave-local DS order
    if (ctrmode){
      // release protocol: fast data sc0 -> ack -> atomic ctr -> truth sc0 sc1
      if (l < 16){
        int bl = l >> 1;
        int hc = l & 1;
        half8 ch = *(const half8*)&scr[bl * 16 + hc * 8];
        const char* df = fastb + (size_t)(t & mask) * GSLOT
                       + (size_t)bl * 1024 + (size_t)g * 32 + (size_t)hc * 16;
        asm volatile("global_store_dwordx4 %0, %1, off sc0"
                     :: "v"(df), "v"(ch) : "memory");
      }
      asm volatile("s_waitcnt vmcnt(0)" ::: "memory");   // data in XCD L2
      if (l == 0){
        int one = 1;
        int* cpub = ctr + ((grp << 9) | (t & mask));
        asm volatile("global_atomic_add %0, %1, off"
                     :: "v"(cpub), "v"(one) : "memory");
      }
      if (l < 16){
        int bl = l >> 1;
        int hc = l & 1;
        half8 ch = *(const half8*)&scr[bl * 16 + hc * 8];
        const char* dt = truth + (size_t)(t & mask) * TSLOT
                       + (size_t)(grp * GRPB + bl) * 1024
                       + (size_t)g * 32 + (size_t)hc * 16;
        asm volatile("global_store_dwordx4 %0, %1, off sc0 sc1"
                     :: "v"(dt), "v"(ch) : "memory");
      }
    } else {
      const int pubN = fast ? 16 : 32;
      if (l < pubN){
        int bl = l >> 1;
        int hc = l & 1;
        half8 ch = *(const half8*)&scr[bl * 16 + hc * 8];
        int gbatch = fast ? (grp * GRPB + bl) : (w * 16 + bl);
        const char* dt = truth + (size_t)(t & mask) * TSLOT
                       + (size_t)gbatch * 1024 + (size_t)g * 32 + (size_t)hc * 16;
        asm volatile("global_store_dwordx4 %0, %1, off sc0 sc1"
                     :: "v"(dt), "v"(ch) : "memory");
      }
      // 5) coarse progress publish (reuse mode only), ordered after restores
      if (reuse && ((t & 7) == 7)){
        asm volatile("s_waitcnt vmcnt(0)" ::: "memory");
        if (l == 0){
          int pv = t + 1;
          const int* pp = fast ? (prog + 128 + grp * 32 + g) : (prog + w * 32 + g);
          asm volatile("global_store_dword %0, %1, off sc0 sc1"
                       :: "v"(pp), "v"(pv) : "memory");
        }
      }
    }
  }
}

// --- K3: logits + log_softmax from truth slot (Lmax-1). 64 blocks x 64. ---
__global__ __launch_bounds__(64) void gru_out(
    const char* __restrict__ truth, const int* __restrict__ lengths,
    const float* __restrict__ wout, const float* __restrict__ bout,
    float* __restrict__ out, int depth)
{
  const int b = blockIdx.x, l = threadIdx.x;
  const int Lmax = lengths[0];
  const _Float16* h = (const _Float16*)(truth
      + (size_t)((Lmax - 1) & (depth - 1)) * TSLOT + (size_t)b * 1024);
  half8 hv = *(const half8*)(h + l * 8);
  float p[NOUT];
  #pragma unroll
  for (int o = 0; o < NOUT; ++o){
    const float* wr = wout + o * HID + l * 8;
    float a = 0.f;
    #pragma unroll
    for (int i = 0; i < 8; ++i) a += wr[i] * (float)hv[i];
    #pragma unroll
    for (int d = 32; d >= 1; d >>= 1) a += __shfl_down(a, d, 64);
    p[o] = a;
  }
  if (l == 0){
    float lg[NOUT], m = -1e30f;
    #pragma unroll
    for (int o = 0; o < NOUT; ++o){
      float v = p[o] + bout[o];
      if (!(v == v)) v = -1.0f;
      lg[o] = v; m = fmaxf(m, v);
    }
    float ssum = 0.f;
    #pragma unroll
    for (int o = 0; o < NOUT; ++o) ssum += __expf(lg[o] - m);
    float ls = __logf(ssum);
    #pragma unroll
    for (int o = 0; o < NOUT; ++o) out[b * NOUT + o] = lg[o] - m - ls;
  }
}

extern "C" void kernel_launch(void* const* d_in, const int* in_sizes, int n_in,
                              void* d_out, int out_size, void* d_ws, size_t ws_size,
                              hipStream_t stream) {
  (void)in_sizes; (void)n_in; (void)out_size;
  const int*   seq     = (const int*)d_in[0];
  const int*   lengths = (const int*)d_in[1];
  const float* emb     = (const float*)d_in[2];
  const float* w_ih    = (const float*)d_in[3];
  const float* w_hh    = (const float*)d_in[4];
  const float* b_ih    = (const float*)d_in[5];
  const float* b_hh    = (const float*)d_in[6];
  const float* w_out   = (const float*)d_in[7];
  const float* b_out   = (const float*)d_in[8];
  float*       outp    = (float*)d_out;

  // ring depth: largest power of two in [16, 512] such that both rings
  // (depth * 128 KiB) + prog/ctr fit the workspace after xg.
  size_t avail = (ws_size > (size_t)XG_BYTES + 32768)
               ? ws_size - (size_t)XG_BYTES - 32768 : 0;
  int depth = 16;
  while (depth < 512 && ((size_t)(depth << 1) * RING2) <= avail) depth <<= 1;

  char* ws = (char*)d_ws;
  ushort_t* xg    = (ushort_t*)ws;                                 // 100,663,296 B
  char*     truth = ws + XG_BYTES;                                 // depth*65,536 B
  char*     fastr = truth + (size_t)depth * TSLOT;                 // depth*65,536 B
  int*      prog  = (int*)(fastr + (size_t)depth * TSLOT);         // 4608 ints

  gru_init<<<depth * 32, 256, 0, stream>>>(truth, prog);
  dim3 g1(SEQL, G3 / 64);
  gru_xgates<<<g1, 256, 0, stream>>>(seq, emb, w_ih, b_ih, xg);
  gru_rec<<<256, 256, 0, stream>>>(xg, w_hh, b_hh, lengths, truth, fastr, prog, depth);
  gru_out<<<BATCH, 64, 0, stream>>>(truth, lengths, w_out, b_out, outp, depth);
}